// Round 17
// baseline (438.473 us; speedup 1.0000x reference)
//
#include <hip/hip_runtime.h>
#include <hip/hip_fp16.h>
#include <hip/hip_bf16.h>

typedef _Float16 f16x8 __attribute__((ext_vector_type(8)));
typedef float f32x4 __attribute__((ext_vector_type(4)));
typedef int v4i __attribute__((ext_vector_type(4)));

// ---------------- small helpers ----------------
typedef const __attribute__((address_space(1))) unsigned int* gas_u32;
typedef __attribute__((address_space(3))) unsigned int* las_u32;

__device__ __forceinline__ void gl_lds16h(const __half* g, __half* l) {
    __builtin_amdgcn_global_load_lds((gas_u32)(const void*)g, (las_u32)(void*)l, 16, 0, 0);
}

// non-temporal 16B load (streaming; does not evict L2-resident write lines)
__device__ __forceinline__ int4 nt_load4(const int* p) {
    v4i r = __builtin_nontemporal_load((const v4i*)p);
    return make_int4(r.x, r.y, r.z, r.w);
}

// accumulate 8 halves (one uint4) into 8 f32 accumulators
__device__ __forceinline__ void acc_half8(float* acc, uint4 raw) {
    union { uint4 u; __half2 h[4]; } pk; pk.u = raw;
    float2 f0 = __half22float2(pk.h[0]);
    float2 f1 = __half22float2(pk.h[1]);
    float2 f2 = __half22float2(pk.h[2]);
    float2 f3 = __half22float2(pk.h[3]);
    acc[0] += f0.x; acc[1] += f0.y; acc[2] += f1.x; acc[3] += f1.y;
    acc[4] += f2.x; acc[5] += f2.y; acc[6] += f3.x; acc[7] += f3.y;
}

// ---------------- W^T conversion ----------------
__global__ __launch_bounds__(256) void convwt_kernel(const float* __restrict__ Wa,
                                                     const float* __restrict__ Wb,
                                                     __half* __restrict__ o) {
    int i = blockIdx.x * 256 + threadIdx.x;  // 16384; i = col*128 + k
    int col = i >> 7, k = i & 127;
    float w = Wb ? ((col < 64) ? Wa[k * 64 + col] : Wb[k * 64 + (col - 64)])
                 : Wa[k * 128 + col];
    o[i] = __float2half(w);
}

// ---------------- degree count ----------------
__global__ __launch_bounds__(256) void cnt_count4_kernel(const int* __restrict__ dst, int* cnt, int E4) {
    int i = blockIdx.x * blockDim.x + threadIdx.x;
    if (i < E4) {
        int4 d = nt_load4(dst + i * 4);
        atomicAdd(&cnt[d.x], 1);
        atomicAdd(&cnt[d.y], 1);
        atomicAdd(&cnt[d.z], 1);
        atomicAdd(&cnt[d.w], 1);
    }
}
__global__ __launch_bounds__(256) void cnt_count_kernel(const int* __restrict__ dst, int* cnt, int E) {
    int i = blockIdx.x * blockDim.x + threadIdx.x;
    if (i < E) atomicAdd(&cnt[dst[i]], 1);
}

// ---------------- exclusive scan ----------------
#define SCAN_CHUNK 4096

__global__ __launch_bounds__(256) void scan_reduce_kernel(const int* __restrict__ cnt, int* bsum, int N) {
    __shared__ int sdata[256];
    int base = blockIdx.x * SCAN_CHUNK;
    int s = 0;
    for (int k = 0; k < 16; ++k) {
        int i = base + k * 256 + threadIdx.x;
        if (i < N) s += cnt[i];
    }
    sdata[threadIdx.x] = s;
    __syncthreads();
    for (int off = 128; off > 0; off >>= 1) {
        if (threadIdx.x < off) sdata[threadIdx.x] += sdata[threadIdx.x + off];
        __syncthreads();
    }
    if (threadIdx.x == 0) bsum[blockIdx.x] = sdata[0];
}

__global__ void scan_bsum_kernel(int* bsum, int B, int* rowptr_end, int E) {
    if (threadIdx.x == 0 && blockIdx.x == 0) {
        int run = 0;
        for (int i = 0; i < B; ++i) { int v = bsum[i]; bsum[i] = run; run += v; }
        *rowptr_end = E;
    }
}

__global__ __launch_bounds__(256) void scan_write_kernel(const int* __restrict__ cnt,
                                                         const int* __restrict__ bsum,
                                                         int* rowptr, int* cursor,
                                                         float* dinv, int N) {
    __shared__ int sdata[256];
    int base = blockIdx.x * SCAN_CHUNK;
    int tbase = base + threadIdx.x * 16;
    int loc[16];
    int s = 0;
    for (int k = 0; k < 16; ++k) {
        int i = tbase + k;
        int v = (i < N) ? cnt[i] : 0;
        loc[k] = s; s += v;
    }
    sdata[threadIdx.x] = s;
    __syncthreads();
    for (int off = 1; off < 256; off <<= 1) {
        int v = sdata[threadIdx.x];
        int add = (threadIdx.x >= off) ? sdata[threadIdx.x - off] : 0;
        __syncthreads();
        sdata[threadIdx.x] = v + add;
        __syncthreads();
    }
    int texcl = (threadIdx.x == 0) ? 0 : sdata[threadIdx.x - 1];
    int boff = bsum[blockIdx.x];
    for (int k = 0; k < 16; ++k) {
        int i = tbase + k;
        if (i < N) {
            int rp = boff + texcl + loc[k];
            rowptr[i] = rp;
            cursor[i] = rp;
            dinv[i] = rsqrtf((float)(cnt[i] + 1));
        }
    }
}

// ---------------- XCD-partitioned csr fill + nt edge loads ----------------
// R12: partitioning keeps each XCD's col writes in a 0.8MB window (135->71us).
// R15 PMC: WRITE still 78MB -> the 50MB edge-read stream LRU-evicts the
// partially-written col lines from L2. nt loads keep the stream out of L2.
#define NPART 8

__global__ __launch_bounds__(256) void csr_fill_part4_kernel(const int* __restrict__ src,
                                                             const int* __restrict__ dst,
                                                             int* cursor, int* __restrict__ col,
                                                             int E4, int pshift) {
    int part = blockIdx.x & (NPART - 1);
    int i = (blockIdx.x >> 3) * blockDim.x + threadIdx.x;
    if (i >= E4) return;
    int4 d = nt_load4(dst + i * 4);
    if ((d.x >> pshift) != part && (d.y >> pshift) != part &&
        (d.z >> pshift) != part && (d.w >> pshift) != part) return;
    int4 s = nt_load4(src + i * 4);
    if ((d.x >> pshift) == part) { int p = atomicAdd(&cursor[d.x], 1); col[p] = s.x; }
    if ((d.y >> pshift) == part) { int p = atomicAdd(&cursor[d.y], 1); col[p] = s.y; }
    if ((d.z >> pshift) == part) { int p = atomicAdd(&cursor[d.z], 1); col[p] = s.z; }
    if ((d.w >> pshift) == part) { int p = atomicAdd(&cursor[d.w], 1); col[p] = s.w; }
}

__global__ __launch_bounds__(256) void csr_fill_kernel(const int* __restrict__ src,
                                                       const int* __restrict__ dst,
                                                       int* cursor, int* __restrict__ col,
                                                       int E) {
    int e = blockIdx.x * blockDim.x + threadIdx.x;
    if (e >= E) return;
    int s = src[e], d = dst[e];
    int pos = atomicAdd(&cursor[d], 1);
    col[pos] = s;
}

// ---------------- MFMA GEMM (R15: kills the W-stream L1 bottleneck) ----------------
#define MT_ROWS 32

__global__ __launch_bounds__(256) void gemm_mfma(const void* __restrict__ hin, int in_f32,
                                                 const __half* __restrict__ Wt,
                                                 const float* __restrict__ dinv,
                                                 __half* __restrict__ th,
                                                 int N, int ntiles) {
    __shared__ __half hl[2][MT_ROWS * 128];  // 2 x 8KB, swizzled chunks

    const int l   = threadIdx.x & 63;
    const int w   = threadIdx.x >> 6;
    const int wrow = (w >> 1) * 16;
    const int c0   = (w & 1) * 64;
    const int l16 = l & 15, lq = l >> 4;

    f16x8 b[4][4];
    #pragma unroll
    for (int ct = 0; ct < 4; ++ct)
        #pragma unroll
        for (int ks = 0; ks < 4; ++ks)
            b[ct][ks] = *(const f16x8*)(Wt + (size_t)(c0 + ct * 16 + l16) * 128 + ks * 32 + lq * 8);

    auto stage = [&](int buf, long long tile) {
        if (tile >= ntiles) return;
        long long row0 = tile * MT_ROWS;
        if (!in_f32 && row0 + MT_ROWS <= N) {
            const __half* hsrc = (const __half*)hin;
            #pragma unroll
            for (int m = 0; m < 2; ++m) {
                int qb = w * 128 + m * 64;
                int q  = qb + l;
                int r = q >> 4, cc = q & 15;
                int csrc = cc ^ (r & 7);
                gl_lds16h(hsrc + (size_t)(row0 + r) * 128 + csrc * 8,
                          &hl[buf][(size_t)qb * 8]);
            }
        } else {
            for (int idx = threadIdx.x; idx < MT_ROWS * 16; idx += 256) {
                int r = idx >> 4, cc = idx & 15;
                long long row = row0 + r;
                __half tmp[8];
                if (row < N) {
                    if (in_f32) {
                        const float* fs = (const float*)hin + row * 128 + cc * 8;
                        #pragma unroll
                        for (int j = 0; j < 8; ++j) tmp[j] = __float2half(fs[j]);
                    } else {
                        const __half* hs = (const __half*)hin + row * 128 + cc * 8;
                        #pragma unroll
                        for (int j = 0; j < 8; ++j) tmp[j] = hs[j];
                    }
                } else {
                    #pragma unroll
                    for (int j = 0; j < 8; ++j) tmp[j] = __float2half(0.f);
                }
                *(uint4*)&hl[buf][(size_t)(r * 16 + (cc ^ (r & 7))) * 8] = *(uint4*)tmp;
            }
        }
    };

    long long tile = blockIdx.x;
    stage(0, tile);
    __syncthreads();
    int cur = 0;

    for (; tile < ntiles; tile += gridDim.x) {
        stage(cur ^ 1, tile + gridDim.x);

        f32x4 acc[4];
        #pragma unroll
        for (int ct = 0; ct < 4; ++ct) acc[ct] = (f32x4){0.f, 0.f, 0.f, 0.f};

        const int r = wrow + l16;
        #pragma unroll
        for (int ks = 0; ks < 4; ++ks) {
            int cchunk = (ks * 4 + lq) ^ (r & 7);
            f16x8 a = *(const f16x8*)&hl[cur][(size_t)(r * 16 + cchunk) * 8];
            #pragma unroll
            for (int ct = 0; ct < 4; ++ct)
                acc[ct] = __builtin_amdgcn_mfma_f32_16x16x32_f16(a, b[ct][ks], acc[ct], 0, 0, 0);
        }

        long long row0 = tile * MT_ROWS;
        #pragma unroll
        for (int i = 0; i < 4; ++i) {
            long long row = row0 + wrow + lq * 4 + i;
            if (row < N) {
                float di = dinv[row];
                #pragma unroll
                for (int ct = 0; ct < 4; ++ct)
                    th[(size_t)row * 128 + c0 + ct * 16 + l16] = __float2half(acc[ct][i] * di);
            }
        }
        __syncthreads();
        cur ^= 1;
    }
}

// ---------------- pull aggregation over f16 t -> f16 h (hidden layers, relu) ----------------
// 8 gathers in flight per lane (MLP; R4 lesson re-applied to the f16 path).
__global__ __launch_bounds__(256) void agg_pull_h16_kernel(const __half* __restrict__ th,
                                                           const int* __restrict__ rowptr,
                                                           const int* __restrict__ col,
                                                           const float* __restrict__ dinv,
                                                           const float* __restrict__ b,
                                                           __half* __restrict__ hh,
                                                           int N) {
    int v = blockIdx.x * 16 + (threadIdx.x >> 4);
    int c = threadIdx.x & 15;
    if (v >= N) return;
    const uint4* tq = (const uint4*)th;
    int beg = rowptr[v], end = rowptr[v + 1];
    float a0[8] = {0,0,0,0,0,0,0,0}, a1[8] = {0,0,0,0,0,0,0,0};
    float a2[8] = {0,0,0,0,0,0,0,0}, a3[8] = {0,0,0,0,0,0,0,0};
    acc_half8(a0, tq[(size_t)v * 16 + c]);  // self-loop (pre-scaled)
    int e = beg;
    for (; e + 7 < end; e += 8) {
        int s0 = col[e],     s1 = col[e + 1], s2 = col[e + 2], s3 = col[e + 3];
        int s4 = col[e + 4], s5 = col[e + 5], s6 = col[e + 6], s7 = col[e + 7];
        uint4 r0 = tq[(size_t)s0 * 16 + c];
        uint4 r1 = tq[(size_t)s1 * 16 + c];
        uint4 r2 = tq[(size_t)s2 * 16 + c];
        uint4 r3 = tq[(size_t)s3 * 16 + c];
        uint4 r4 = tq[(size_t)s4 * 16 + c];
        uint4 r5 = tq[(size_t)s5 * 16 + c];
        uint4 r6 = tq[(size_t)s6 * 16 + c];
        uint4 r7 = tq[(size_t)s7 * 16 + c];
        acc_half8(a0, r0); acc_half8(a1, r1); acc_half8(a2, r2); acc_half8(a3, r3);
        acc_half8(a0, r4); acc_half8(a1, r5); acc_half8(a2, r6); acc_half8(a3, r7);
    }
    for (; e + 3 < end; e += 4) {
        int s0 = col[e], s1 = col[e + 1], s2 = col[e + 2], s3 = col[e + 3];
        uint4 r0 = tq[(size_t)s0 * 16 + c];
        uint4 r1 = tq[(size_t)s1 * 16 + c];
        uint4 r2 = tq[(size_t)s2 * 16 + c];
        uint4 r3 = tq[(size_t)s3 * 16 + c];
        acc_half8(a0, r0); acc_half8(a1, r1); acc_half8(a2, r2); acc_half8(a3, r3);
    }
    for (; e < end; ++e) acc_half8(a0, tq[(size_t)col[e] * 16 + c]);
    float di = dinv[v];
    float4 b0 = *(const float4*)(b + c * 8);
    float4 b1v = *(const float4*)(b + c * 8 + 4);
    __half ov[8];
    #pragma unroll
    for (int i = 0; i < 8; ++i) {
        float bb = (i < 4) ? (&b0.x)[i] : (&b1v.x)[i - 4];
        float s = (a0[i] + a1[i]) + (a2[i] + a3[i]);
        ov[i] = __float2half(fmaxf(fmaf(s, di, bb), 0.f));
    }
    *(uint4*)&hh[(size_t)v * 128 + c * 8] = *(uint4*)ov;
}

// final: lane chunks c<8 -> mu, c>=8 -> logstd (f32 split output)
__global__ __launch_bounds__(256) void agg_pull_final_h_kernel(const __half* __restrict__ th,
                                                               const int* __restrict__ rowptr,
                                                               const int* __restrict__ col,
                                                               const float* __restrict__ dinv,
                                                               const float* __restrict__ bmu,
                                                               const float* __restrict__ bls,
                                                               float* __restrict__ out,
                                                               int N) {
    int v = blockIdx.x * 16 + (threadIdx.x >> 4);
    int c = threadIdx.x & 15;
    if (v >= N) return;
    const uint4* tq = (const uint4*)th;
    int beg = rowptr[v], end = rowptr[v + 1];
    float a0[8] = {0,0,0,0,0,0,0,0}, a1[8] = {0,0,0,0,0,0,0,0};
    float a2[8] = {0,0,0,0,0,0,0,0}, a3[8] = {0,0,0,0,0,0,0,0};
    acc_half8(a0, tq[(size_t)v * 16 + c]);
    int e = beg;
    for (; e + 7 < end; e += 8) {
        int s0 = col[e],     s1 = col[e + 1], s2 = col[e + 2], s3 = col[e + 3];
        int s4 = col[e + 4], s5 = col[e + 5], s6 = col[e + 6], s7 = col[e + 7];
        uint4 r0 = tq[(size_t)s0 * 16 + c];
        uint4 r1 = tq[(size_t)s1 * 16 + c];
        uint4 r2 = tq[(size_t)s2 * 16 + c];
        uint4 r3 = tq[(size_t)s3 * 16 + c];
        uint4 r4 = tq[(size_t)s4 * 16 + c];
        uint4 r5 = tq[(size_t)s5 * 16 + c];
        uint4 r6 = tq[(size_t)s6 * 16 + c];
        uint4 r7 = tq[(size_t)s7 * 16 + c];
        acc_half8(a0, r0); acc_half8(a1, r1); acc_half8(a2, r2); acc_half8(a3, r3);
        acc_half8(a0, r4); acc_half8(a1, r5); acc_half8(a2, r6); acc_half8(a3, r7);
    }
    for (; e + 3 < end; e += 4) {
        int s0 = col[e], s1 = col[e + 1], s2 = col[e + 2], s3 = col[e + 3];
        uint4 r0 = tq[(size_t)s0 * 16 + c];
        uint4 r1 = tq[(size_t)s1 * 16 + c];
        uint4 r2 = tq[(size_t)s2 * 16 + c];
        uint4 r3 = tq[(size_t)s3 * 16 + c];
        acc_half8(a0, r0); acc_half8(a1, r1); acc_half8(a2, r2); acc_half8(a3, r3);
    }
    for (; e < end; ++e) acc_half8(a0, tq[(size_t)col[e] * 16 + c]);
    float di = dinv[v];
    const float* bp = (c < 8) ? (bmu + c * 8) : (bls + (c - 8) * 8);
    float* obase = (c < 8) ? (out + (size_t)v * 64 + c * 8)
                           : (out + (size_t)N * 64 + (size_t)v * 64 + (size_t)(c - 8) * 8);
    float4 b0 = *(const float4*)bp;
    float4 b1v = *(const float4*)(bp + 4);
    float o[8];
    #pragma unroll
    for (int i = 0; i < 8; ++i) {
        float bb = (i < 4) ? (&b0.x)[i] : (&b1v.x)[i - 4];
        float s = (a0[i] + a1[i]) + (a2[i] + a3[i]);
        o[i] = fmaf(s, di, bb);
    }
    ((float4*)obase)[0] = make_float4(o[0], o[1], o[2], o[3]);
    ((float4*)obase)[1] = make_float4(o[4], o[5], o[6], o[7]);
}

// ---------------- fallback (atomic scatter, f32) kernels ----------------
__device__ __forceinline__ float4 f4_fma(float4 a, float s, float4 acc) {
    acc.x = fmaf(a.x, s, acc.x); acc.y = fmaf(a.y, s, acc.y);
    acc.z = fmaf(a.z, s, acc.z); acc.w = fmaf(a.w, s, acc.w);
    return acc;
}
__global__ __launch_bounds__(256) void deg_init_kernel(float* deg, int N) {
    int i = blockIdx.x * blockDim.x + threadIdx.x;
    if (i < N) deg[i] = 1.0f;
}
__global__ __launch_bounds__(256) void deg_count_kernel(const int* __restrict__ dst, float* deg, int E) {
    int i = blockIdx.x * blockDim.x + threadIdx.x;
    if (i < E) unsafeAtomicAdd(&deg[dst[i]], 1.0f);
}
__global__ __launch_bounds__(256) void deg_rsqrt_kernel(float* deg, int N) {
    int i = blockIdx.x * blockDim.x + threadIdx.x;
    if (i < N) deg[i] = rsqrtf(deg[i]);
}
__global__ __launch_bounds__(256) void gemm128_kernel(const float* __restrict__ h,
                                                      const float* __restrict__ Wa,
                                                      const float* __restrict__ Wb,
                                                      float* __restrict__ t,
                                                      int N, int relu) {
    __shared__ float Wl[128 * 128];
    __shared__ float hl[2][128];
    for (int i = threadIdx.x; i < 128 * 128; i += 256) {
        int k = i >> 7, j = i & 127;
        float w;
        if (Wb) w = (j < 64) ? Wa[k * 64 + j] : Wb[k * 64 + (j - 64)];
        else    w = Wa[i];
        Wl[i] = w;
    }
    __syncthreads();
    int col = threadIdx.x & 127;
    int r   = threadIdx.x >> 7;
    for (long long pair = blockIdx.x; pair * 2 < N; pair += gridDim.x) {
        int row0 = (int)(pair * 2);
        {
            int rr = threadIdx.x >> 7, k = threadIdx.x & 127;
            int row = row0 + rr;
            float v = (row < N) ? h[(size_t)row * 128 + k] : 0.0f;
            if (relu) v = fmaxf(v, 0.0f);
            hl[rr][k] = v;
        }
        __syncthreads();
        float acc = 0.0f;
        #pragma unroll
        for (int k = 0; k < 128; k += 4) {
            float4 hv = *(const float4*)&hl[r][k];
            acc += hv.x * Wl[(k + 0) * 128 + col];
            acc += hv.y * Wl[(k + 1) * 128 + col];
            acc += hv.z * Wl[(k + 2) * 128 + col];
            acc += hv.w * Wl[(k + 3) * 128 + col];
        }
        int row = row0 + r;
        if (row < N) t[(size_t)row * 128 + col] = acc;
        __syncthreads();
    }
}
__global__ __launch_bounds__(256) void init_self_kernel(const float4* __restrict__ t4,
                                                        const float* __restrict__ dinv,
                                                        const float* __restrict__ b,
                                                        float4* __restrict__ out, int N) {
    int idx = blockIdx.x * blockDim.x + threadIdx.x;
    int v = idx >> 5, c = idx & 31;
    if (v >= N) return;
    float di = dinv[v];
    float s = di * di;
    float4 x = t4[(size_t)v * 32 + c];
    float4 bb = ((const float4*)b)[c];
    out[(size_t)v * 32 + c] = make_float4(fmaf(x.x, s, bb.x), fmaf(x.y, s, bb.y),
                                          fmaf(x.z, s, bb.z), fmaf(x.w, s, bb.w));
}
__global__ __launch_bounds__(256) void init_final_kernel(const float4* __restrict__ t4,
                                                         const float* __restrict__ dinv,
                                                         const float* __restrict__ bmu,
                                                         const float* __restrict__ bls,
                                                         float4* __restrict__ out4, int N) {
    int idx = blockIdx.x * blockDim.x + threadIdx.x;
    int v = idx >> 5, c = idx & 31;
    if (v >= N) return;
    int half = c >> 4, cc = c & 15;
    float di = dinv[v];
    float s = di * di;
    float4 x = t4[(size_t)v * 32 + c];
    float4 bb = half ? ((const float4*)bls)[cc] : ((const float4*)bmu)[cc];
    out4[(size_t)half * N * 16 + (size_t)v * 16 + cc] =
        make_float4(fmaf(x.x, s, bb.x), fmaf(x.y, s, bb.y),
                    fmaf(x.z, s, bb.z), fmaf(x.w, s, bb.w));
}
__global__ __launch_bounds__(256) void agg_edge_kernel(const float4* __restrict__ t4,
                                                       const int* __restrict__ src,
                                                       const int* __restrict__ dst,
                                                       const float* __restrict__ dinv,
                                                       float* __restrict__ out, int E) {
    int idx = blockIdx.x * blockDim.x + threadIdx.x;
    int e = idx >> 5, c = idx & 31;
    if (e >= E) return;
    int s = src[e], d = dst[e];
    float w = dinv[s] * dinv[d];
    float4 v = t4[(size_t)s * 32 + c];
    float* o = out + (size_t)d * 128 + c * 4;
    unsafeAtomicAdd(o + 0, v.x * w);
    unsafeAtomicAdd(o + 1, v.y * w);
    unsafeAtomicAdd(o + 2, v.z * w);
    unsafeAtomicAdd(o + 3, v.w * w);
}
__global__ __launch_bounds__(256) void agg_edge_final_kernel(const float4* __restrict__ t4,
                                                             const int* __restrict__ src,
                                                             const int* __restrict__ dst,
                                                             const float* __restrict__ dinv,
                                                             float* __restrict__ out, int N, int E) {
    int idx = blockIdx.x * blockDim.x + threadIdx.x;
    int e = idx >> 5, c = idx & 31;
    if (e >= E) return;
    int s = src[e], d = dst[e];
    int half = c >> 4, cc = c & 15;
    float w = dinv[s] * dinv[d];
    float4 v = t4[(size_t)s * 32 + c];
    float* o = out + (size_t)half * N * 64 + (size_t)d * 64 + cc * 4;
    unsafeAtomicAdd(o + 0, v.x * w);
    unsafeAtomicAdd(o + 1, v.y * w);
    unsafeAtomicAdd(o + 2, v.z * w);
    unsafeAtomicAdd(o + 3, v.w * w);
}

// ---------------- launch ----------------
extern "C" void kernel_launch(void* const* d_in, const int* in_sizes, int n_in,
                              void* d_out, int out_size, void* d_ws, size_t ws_size,
                              hipStream_t stream) {
    const float* x   = (const float*)d_in[0];
    const int*   ei  = (const int*)d_in[1];
    const float* W1  = (const float*)d_in[2];
    const float* b1  = (const float*)d_in[3];
    const float* W2  = (const float*)d_in[4];
    const float* b2  = (const float*)d_in[5];
    const float* Wmu = (const float*)d_in[6];
    const float* bmu = (const float*)d_in[7];
    const float* Wls = (const float*)d_in[8];
    const float* bls = (const float*)d_in[9];

    const int N = in_sizes[0] / 128;
    const int E = in_sizes[1] / 2;
    const int* src = ei;
    const int* dst = ei + E;

    float* out = (float*)d_out;

    auto align256 = [](size_t o) { return (o + 255) & ~(size_t)255; };
    const int B1 = (N + SCAN_CHUNK - 1) / SCAN_CHUNK;

    size_t off = 0;
    size_t o_dinv   = off; off = align256(off + (size_t)N * 4);
    size_t o_t      = off; off = align256(off + (size_t)N * 128 * 4);
    size_t o_rowptr = off; off = align256(off + (size_t)(N + 1) * 4);
    size_t o_cursor = off; off = align256(off + (size_t)N * 4);
    size_t o_bsum   = off; off = align256(off + (size_t)B1 * 4);
    size_t o_col    = off; off = align256(off + (size_t)E * 4);
    size_t o_wt     = off; off = align256(off + (size_t)3 * 128 * 128 * 2);
    size_t need = off;

    float*  dinv = (float*)((char*)d_ws + o_dinv);
    float*  tf   = (float*)((char*)d_ws + o_t);
    __half* th   = (__half*)((char*)d_ws + o_t);
    __half* hh   = (__half*)((char*)d_ws + o_t) + (size_t)N * 128;

    const int TB = 256;
    int gN = (N + TB - 1) / TB;
    int gE = (E + TB - 1) / TB;
    int ntiles = (N + MT_ROWS - 1) / MT_ROWS;

    if (ws_size >= need) {
        int* rowptr = (int*)((char*)d_ws + o_rowptr);
        int* cursor = (int*)((char*)d_ws + o_cursor);
        int* bsum   = (int*)((char*)d_ws + o_bsum);
        int* col    = (int*)((char*)d_ws + o_col);
        __half* wt1 = (__half*)((char*)d_ws + o_wt);
        __half* wt2 = wt1 + 128 * 128;
        __half* wt3 = wt2 + 128 * 128;

        const bool vec4 = ((E & 3) == 0) && ((((uintptr_t)ei) & 15) == 0);
        const int E4 = E >> 2;
        int gE4 = (E4 + TB - 1) / TB;

        int pshift = 0;
        while (((N - 1) >> pshift) >= NPART) ++pshift;

        convwt_kernel<<<64, TB, 0, stream>>>(W1, nullptr, wt1);
        convwt_kernel<<<64, TB, 0, stream>>>(W2, nullptr, wt2);
        convwt_kernel<<<64, TB, 0, stream>>>(Wmu, Wls, wt3);

        hipMemsetAsync(cursor, 0, (size_t)N * 4, stream);
        if (vec4)
            cnt_count4_kernel<<<gE4, TB, 0, stream>>>(dst, cursor, E4);
        else
            cnt_count_kernel<<<gE, TB, 0, stream>>>(dst, cursor, E);
        scan_reduce_kernel<<<B1, TB, 0, stream>>>(cursor, bsum, N);
        scan_bsum_kernel<<<1, 64, 0, stream>>>(bsum, B1, rowptr + N, E);
        scan_write_kernel<<<B1, TB, 0, stream>>>(cursor, bsum, rowptr, cursor, dinv, N);
        if (vec4)
            csr_fill_part4_kernel<<<gE4 * NPART, TB, 0, stream>>>(src, dst, cursor, col, E4, pshift);
        else
            csr_fill_kernel<<<gE, TB, 0, stream>>>(src, dst, cursor, col, E);

        int gPull = (N + 15) / 16;
        gemm_mfma<<<1024, TB, 0, stream>>>(x, 1, wt1, dinv, th, N, ntiles);
        agg_pull_h16_kernel<<<gPull, TB, 0, stream>>>(th, rowptr, col, dinv, b1, hh, N);
        gemm_mfma<<<1024, TB, 0, stream>>>(hh, 0, wt2, dinv, th, N, ntiles);
        agg_pull_h16_kernel<<<gPull, TB, 0, stream>>>(th, rowptr, col, dinv, b2, hh, N);
        gemm_mfma<<<1024, TB, 0, stream>>>(hh, 0, wt3, dinv, th, N, ntiles);
        agg_pull_final_h_kernel<<<gPull, TB, 0, stream>>>(th, rowptr, col, dinv, bmu, bls, out, N);
    } else {
        int gN32  = (N * 32 + TB - 1) / TB;
        int gE32h = (int)(((long long)E * 32 + TB - 1) / TB);
        deg_init_kernel<<<gN, TB, 0, stream>>>(dinv, N);
        deg_count_kernel<<<gE, TB, 0, stream>>>(dst, dinv, E);
        deg_rsqrt_kernel<<<gN, TB, 0, stream>>>(dinv, N);

        gemm128_kernel<<<2048, TB, 0, stream>>>(x, W1, nullptr, tf, N, 0);
        init_self_kernel<<<gN32, TB, 0, stream>>>((const float4*)tf, dinv, b1, (float4*)out, N);
        agg_edge_kernel<<<gE32h, TB, 0, stream>>>((const float4*)tf, src, dst, dinv, out, E);

        gemm128_kernel<<<2048, TB, 0, stream>>>(out, W2, nullptr, tf, N, 1);
        init_self_kernel<<<gN32, TB, 0, stream>>>((const float4*)tf, dinv, b2, (float4*)out, N);
        agg_edge_kernel<<<gE32h, TB, 0, stream>>>((const float4*)tf, src, dst, dinv, out, E);

        gemm128_kernel<<<2048, TB, 0, stream>>>(out, Wmu, Wls, tf, N, 1);
        init_final_kernel<<<gN32, TB, 0, stream>>>((const float4*)tf, dinv, bmu, bls, (float4*)out, N);
        agg_edge_final_kernel<<<gE32h, TB, 0, stream>>>((const float4*)tf, src, dst, dinv, out, N, E);
    }
}

// Round 18
// 423.573 us; speedup vs baseline: 1.0352x; 1.0352x over previous
//
#include <hip/hip_runtime.h>
#include <hip/hip_fp16.h>
#include <hip/hip_bf16.h>

typedef _Float16 f16x8 __attribute__((ext_vector_type(8)));
typedef float f32x4 __attribute__((ext_vector_type(4)));

// ---------------- small helpers ----------------
typedef const __attribute__((address_space(1))) unsigned int* gas_u32;
typedef __attribute__((address_space(3))) unsigned int* las_u32;

__device__ __forceinline__ void gl_lds16h(const __half* g, __half* l) {
    __builtin_amdgcn_global_load_lds((gas_u32)(const void*)g, (las_u32)(void*)l, 16, 0, 0);
}

// accumulate 8 halves (one uint4) into 8 f32 accumulators
__device__ __forceinline__ void acc_half8(float* acc, uint4 raw) {
    union { uint4 u; __half2 h[4]; } pk; pk.u = raw;
    float2 f0 = __half22float2(pk.h[0]);
    float2 f1 = __half22float2(pk.h[1]);
    float2 f2 = __half22float2(pk.h[2]);
    float2 f3 = __half22float2(pk.h[3]);
    acc[0] += f0.x; acc[1] += f0.y; acc[2] += f1.x; acc[3] += f1.y;
    acc[4] += f2.x; acc[5] += f2.y; acc[6] += f3.x; acc[7] += f3.y;
}

// ---------------- W^T conversion (all 3 layers in one launch) ----------------
// blocks [0,64): W1 -> wt; [64,128): W2 -> wt+16384; [128,192): [Wmu|Wls] -> wt+32768
__global__ __launch_bounds__(256) void convwt_all_kernel(const float* __restrict__ W1,
                                                         const float* __restrict__ W2,
                                                         const float* __restrict__ Wmu,
                                                         const float* __restrict__ Wls,
                                                         __half* __restrict__ wt) {
    int which = blockIdx.x >> 6;
    int i = (blockIdx.x & 63) * 256 + threadIdx.x;  // i = col*128 + k
    int col = i >> 7, k = i & 127;
    float w;
    if (which == 0)      w = W1[k * 128 + col];
    else if (which == 1) w = W2[k * 128 + col];
    else                 w = (col < 64) ? Wmu[k * 64 + col] : Wls[k * 64 + (col - 64)];
    wt[which * 16384 + i] = __float2half(w);
}

// ---------------- degree count ----------------
__global__ __launch_bounds__(256) void cnt_count4_kernel(const int4* __restrict__ dst4, int* cnt, int E4) {
    int i = blockIdx.x * blockDim.x + threadIdx.x;
    if (i < E4) {
        int4 d = dst4[i];
        atomicAdd(&cnt[d.x], 1);
        atomicAdd(&cnt[d.y], 1);
        atomicAdd(&cnt[d.z], 1);
        atomicAdd(&cnt[d.w], 1);
    }
}
__global__ __launch_bounds__(256) void cnt_count_kernel(const int* __restrict__ dst, int* cnt, int E) {
    int i = blockIdx.x * blockDim.x + threadIdx.x;
    if (i < E) atomicAdd(&cnt[dst[i]], 1);
}

// ---------------- exclusive scan ----------------
#define SCAN_CHUNK 4096

__global__ __launch_bounds__(256) void scan_reduce_kernel(const int* __restrict__ cnt, int* bsum, int N) {
    __shared__ int sdata[256];
    int base = blockIdx.x * SCAN_CHUNK;
    int s = 0;
    for (int k = 0; k < 16; ++k) {
        int i = base + k * 256 + threadIdx.x;
        if (i < N) s += cnt[i];
    }
    sdata[threadIdx.x] = s;
    __syncthreads();
    for (int off = 128; off > 0; off >>= 1) {
        if (threadIdx.x < off) sdata[threadIdx.x] += sdata[threadIdx.x + off];
        __syncthreads();
    }
    if (threadIdx.x == 0) bsum[blockIdx.x] = sdata[0];
}

__global__ void scan_bsum_kernel(int* bsum, int B, int* rowptr_end, int E) {
    if (threadIdx.x == 0 && blockIdx.x == 0) {
        int run = 0;
        for (int i = 0; i < B; ++i) { int v = bsum[i]; bsum[i] = run; run += v; }
        *rowptr_end = E;
    }
}

__global__ __launch_bounds__(256) void scan_write_kernel(const int* __restrict__ cnt,
                                                         const int* __restrict__ bsum,
                                                         int* rowptr, int* cursor,
                                                         float* dinv, int N) {
    __shared__ int sdata[256];
    int base = blockIdx.x * SCAN_CHUNK;
    int tbase = base + threadIdx.x * 16;
    int loc[16];
    int s = 0;
    for (int k = 0; k < 16; ++k) {
        int i = tbase + k;
        int v = (i < N) ? cnt[i] : 0;
        loc[k] = s; s += v;
    }
    sdata[threadIdx.x] = s;
    __syncthreads();
    for (int off = 1; off < 256; off <<= 1) {
        int v = sdata[threadIdx.x];
        int add = (threadIdx.x >= off) ? sdata[threadIdx.x - off] : 0;
        __syncthreads();
        sdata[threadIdx.x] = v + add;
        __syncthreads();
    }
    int texcl = (threadIdx.x == 0) ? 0 : sdata[threadIdx.x - 1];
    int boff = bsum[blockIdx.x];
    for (int k = 0; k < 16; ++k) {
        int i = tbase + k;
        if (i < N) {
            int rp = boff + texcl + loc[k];
            rowptr[i] = rp;
            cursor[i] = rp;
            dinv[i] = rsqrtf((float)(cnt[i] + 1));
        }
    }
}

// ---------------- XCD-partitioned csr fill (R12 mechanism; R16 nt-load variant reverted) ----------------
#define NPART 8

__global__ __launch_bounds__(256) void csr_fill_part4_kernel(const int4* __restrict__ src4,
                                                             const int4* __restrict__ dst4,
                                                             int* cursor, int* __restrict__ col,
                                                             int E4, int pshift) {
    int part = blockIdx.x & (NPART - 1);
    int i = (blockIdx.x >> 3) * blockDim.x + threadIdx.x;
    if (i >= E4) return;
    int4 s = src4[i];
    int4 d = dst4[i];
    if ((d.x >> pshift) == part) { int p = atomicAdd(&cursor[d.x], 1); col[p] = s.x; }
    if ((d.y >> pshift) == part) { int p = atomicAdd(&cursor[d.y], 1); col[p] = s.y; }
    if ((d.z >> pshift) == part) { int p = atomicAdd(&cursor[d.z], 1); col[p] = s.z; }
    if ((d.w >> pshift) == part) { int p = atomicAdd(&cursor[d.w], 1); col[p] = s.w; }
}

__global__ __launch_bounds__(256) void csr_fill_kernel(const int* __restrict__ src,
                                                       const int* __restrict__ dst,
                                                       int* cursor, int* __restrict__ col,
                                                       int E) {
    int e = blockIdx.x * blockDim.x + threadIdx.x;
    if (e >= E) return;
    int s = src[e], d = dst[e];
    int pos = atomicAdd(&cursor[d], 1);
    col[pos] = s;
}

// ---------------- MFMA GEMM (R15: W^T in VGPRs kills the W-stream bottleneck) ----------------
#define MT_ROWS 32

__global__ __launch_bounds__(256) void gemm_mfma(const void* __restrict__ hin, int in_f32,
                                                 const __half* __restrict__ Wt,
                                                 const float* __restrict__ dinv,
                                                 __half* __restrict__ th,
                                                 int N, int ntiles) {
    __shared__ __half hl[2][MT_ROWS * 128];  // 2 x 8KB, swizzled chunks

    const int l   = threadIdx.x & 63;
    const int w   = threadIdx.x >> 6;
    const int wrow = (w >> 1) * 16;
    const int c0   = (w & 1) * 64;
    const int l16 = l & 15, lq = l >> 4;

    f16x8 b[4][4];
    #pragma unroll
    for (int ct = 0; ct < 4; ++ct)
        #pragma unroll
        for (int ks = 0; ks < 4; ++ks)
            b[ct][ks] = *(const f16x8*)(Wt + (size_t)(c0 + ct * 16 + l16) * 128 + ks * 32 + lq * 8);

    auto stage = [&](int buf, long long tile) {
        if (tile >= ntiles) return;
        long long row0 = tile * MT_ROWS;
        if (!in_f32 && row0 + MT_ROWS <= N) {
            const __half* hsrc = (const __half*)hin;
            #pragma unroll
            for (int m = 0; m < 2; ++m) {
                int qb = w * 128 + m * 64;
                int q  = qb + l;
                int r = q >> 4, cc = q & 15;
                int csrc = cc ^ (r & 7);
                gl_lds16h(hsrc + (size_t)(row0 + r) * 128 + csrc * 8,
                          &hl[buf][(size_t)qb * 8]);
            }
        } else {
            for (int idx = threadIdx.x; idx < MT_ROWS * 16; idx += 256) {
                int r = idx >> 4, cc = idx & 15;
                long long row = row0 + r;
                __half tmp[8];
                if (row < N) {
                    if (in_f32) {
                        const float* fs = (const float*)hin + row * 128 + cc * 8;
                        #pragma unroll
                        for (int j = 0; j < 8; ++j) tmp[j] = __float2half(fs[j]);
                    } else {
                        const __half* hs = (const __half*)hin + row * 128 + cc * 8;
                        #pragma unroll
                        for (int j = 0; j < 8; ++j) tmp[j] = hs[j];
                    }
                } else {
                    #pragma unroll
                    for (int j = 0; j < 8; ++j) tmp[j] = __float2half(0.f);
                }
                *(uint4*)&hl[buf][(size_t)(r * 16 + (cc ^ (r & 7))) * 8] = *(uint4*)tmp;
            }
        }
    };

    long long tile = blockIdx.x;
    stage(0, tile);
    __syncthreads();
    int cur = 0;

    for (; tile < ntiles; tile += gridDim.x) {
        stage(cur ^ 1, tile + gridDim.x);

        f32x4 acc[4];
        #pragma unroll
        for (int ct = 0; ct < 4; ++ct) acc[ct] = (f32x4){0.f, 0.f, 0.f, 0.f};

        const int r = wrow + l16;
        #pragma unroll
        for (int ks = 0; ks < 4; ++ks) {
            int cchunk = (ks * 4 + lq) ^ (r & 7);
            f16x8 a = *(const f16x8*)&hl[cur][(size_t)(r * 16 + cchunk) * 8];
            #pragma unroll
            for (int ct = 0; ct < 4; ++ct)
                acc[ct] = __builtin_amdgcn_mfma_f32_16x16x32_f16(a, b[ct][ks], acc[ct], 0, 0, 0);
        }

        long long row0 = tile * MT_ROWS;
        #pragma unroll
        for (int i = 0; i < 4; ++i) {
            long long row = row0 + wrow + lq * 4 + i;
            if (row < N) {
                float di = dinv[row];
                #pragma unroll
                for (int ct = 0; ct < 4; ++ct)
                    th[(size_t)row * 128 + c0 + ct * 16 + l16] = __float2half(acc[ct][i] * di);
            }
        }
        __syncthreads();
        cur ^= 1;
    }
}

// ---------------- pull aggregation over f16 t -> f16 h (hidden layers, relu) ----------------
__global__ __launch_bounds__(256) void agg_pull_h16_kernel(const __half* __restrict__ th,
                                                           const int* __restrict__ rowptr,
                                                           const int* __restrict__ col,
                                                           const float* __restrict__ dinv,
                                                           const float* __restrict__ b,
                                                           __half* __restrict__ hh,
                                                           int N) {
    int v = blockIdx.x * 16 + (threadIdx.x >> 4);
    int c = threadIdx.x & 15;
    if (v >= N) return;
    const uint4* tq = (const uint4*)th;
    int beg = rowptr[v], end = rowptr[v + 1];
    float a0[8] = {0,0,0,0,0,0,0,0}, a1[8] = {0,0,0,0,0,0,0,0};
    float a2[8] = {0,0,0,0,0,0,0,0}, a3[8] = {0,0,0,0,0,0,0,0};
    acc_half8(a0, tq[(size_t)v * 16 + c]);  // self-loop (pre-scaled)
    int e = beg;
    for (; e + 3 < end; e += 4) {
        int s0 = col[e], s1 = col[e + 1], s2 = col[e + 2], s3 = col[e + 3];
        uint4 r0 = tq[(size_t)s0 * 16 + c];
        uint4 r1 = tq[(size_t)s1 * 16 + c];
        uint4 r2 = tq[(size_t)s2 * 16 + c];
        uint4 r3 = tq[(size_t)s3 * 16 + c];
        acc_half8(a0, r0); acc_half8(a1, r1); acc_half8(a2, r2); acc_half8(a3, r3);
    }
    for (; e < end; ++e) acc_half8(a0, tq[(size_t)col[e] * 16 + c]);
    float di = dinv[v];
    float4 b0 = *(const float4*)(b + c * 8);
    float4 b1v = *(const float4*)(b + c * 8 + 4);
    __half ov[8];
    #pragma unroll
    for (int i = 0; i < 8; ++i) {
        float bb = (i < 4) ? (&b0.x)[i] : (&b1v.x)[i - 4];
        float s = (a0[i] + a1[i]) + (a2[i] + a3[i]);
        ov[i] = __float2half(fmaxf(fmaf(s, di, bb), 0.f));
    }
    *(uint4*)&hh[(size_t)v * 128 + c * 8] = *(uint4*)ov;
}

// final: lane chunks c<8 -> mu, c>=8 -> logstd (f32 split output)
__global__ __launch_bounds__(256) void agg_pull_final_h_kernel(const __half* __restrict__ th,
                                                               const int* __restrict__ rowptr,
                                                               const int* __restrict__ col,
                                                               const float* __restrict__ dinv,
                                                               const float* __restrict__ bmu,
                                                               const float* __restrict__ bls,
                                                               float* __restrict__ out,
                                                               int N) {
    int v = blockIdx.x * 16 + (threadIdx.x >> 4);
    int c = threadIdx.x & 15;
    if (v >= N) return;
    const uint4* tq = (const uint4*)th;
    int beg = rowptr[v], end = rowptr[v + 1];
    float a0[8] = {0,0,0,0,0,0,0,0}, a1[8] = {0,0,0,0,0,0,0,0};
    float a2[8] = {0,0,0,0,0,0,0,0}, a3[8] = {0,0,0,0,0,0,0,0};
    acc_half8(a0, tq[(size_t)v * 16 + c]);
    int e = beg;
    for (; e + 3 < end; e += 4) {
        int s0 = col[e], s1 = col[e + 1], s2 = col[e + 2], s3 = col[e + 3];
        uint4 r0 = tq[(size_t)s0 * 16 + c];
        uint4 r1 = tq[(size_t)s1 * 16 + c];
        uint4 r2 = tq[(size_t)s2 * 16 + c];
        uint4 r3 = tq[(size_t)s3 * 16 + c];
        acc_half8(a0, r0); acc_half8(a1, r1); acc_half8(a2, r2); acc_half8(a3, r3);
    }
    for (; e < end; ++e) acc_half8(a0, tq[(size_t)col[e] * 16 + c]);
    float di = dinv[v];
    const float* bp = (c < 8) ? (bmu + c * 8) : (bls + (c - 8) * 8);
    float* obase = (c < 8) ? (out + (size_t)v * 64 + c * 8)
                           : (out + (size_t)N * 64 + (size_t)v * 64 + (size_t)(c - 8) * 8);
    float4 b0 = *(const float4*)bp;
    float4 b1v = *(const float4*)(bp + 4);
    float o[8];
    #pragma unroll
    for (int i = 0; i < 8; ++i) {
        float bb = (i < 4) ? (&b0.x)[i] : (&b1v.x)[i - 4];
        float s = (a0[i] + a1[i]) + (a2[i] + a3[i]);
        o[i] = fmaf(s, di, bb);
    }
    ((float4*)obase)[0] = make_float4(o[0], o[1], o[2], o[3]);
    ((float4*)obase)[1] = make_float4(o[4], o[5], o[6], o[7]);
}

// ---------------- fallback (atomic scatter, f32) kernels ----------------
__device__ __forceinline__ float4 f4_fma(float4 a, float s, float4 acc) {
    acc.x = fmaf(a.x, s, acc.x); acc.y = fmaf(a.y, s, acc.y);
    acc.z = fmaf(a.z, s, acc.z); acc.w = fmaf(a.w, s, acc.w);
    return acc;
}
__global__ __launch_bounds__(256) void deg_init_kernel(float* deg, int N) {
    int i = blockIdx.x * blockDim.x + threadIdx.x;
    if (i < N) deg[i] = 1.0f;
}
__global__ __launch_bounds__(256) void deg_count_kernel(const int* __restrict__ dst, float* deg, int E) {
    int i = blockIdx.x * blockDim.x + threadIdx.x;
    if (i < E) unsafeAtomicAdd(&deg[dst[i]], 1.0f);
}
__global__ __launch_bounds__(256) void deg_rsqrt_kernel(float* deg, int N) {
    int i = blockIdx.x * blockDim.x + threadIdx.x;
    if (i < N) deg[i] = rsqrtf(deg[i]);
}
__global__ __launch_bounds__(256) void gemm128_kernel(const float* __restrict__ h,
                                                      const float* __restrict__ Wa,
                                                      const float* __restrict__ Wb,
                                                      float* __restrict__ t,
                                                      int N, int relu) {
    __shared__ float Wl[128 * 128];
    __shared__ float hl[2][128];
    for (int i = threadIdx.x; i < 128 * 128; i += 256) {
        int k = i >> 7, j = i & 127;
        float w;
        if (Wb) w = (j < 64) ? Wa[k * 64 + j] : Wb[k * 64 + (j - 64)];
        else    w = Wa[i];
        Wl[i] = w;
    }
    __syncthreads();
    int col = threadIdx.x & 127;
    int r   = threadIdx.x >> 7;
    for (long long pair = blockIdx.x; pair * 2 < N; pair += gridDim.x) {
        int row0 = (int)(pair * 2);
        {
            int rr = threadIdx.x >> 7, k = threadIdx.x & 127;
            int row = row0 + rr;
            float v = (row < N) ? h[(size_t)row * 128 + k] : 0.0f;
            if (relu) v = fmaxf(v, 0.0f);
            hl[rr][k] = v;
        }
        __syncthreads();
        float acc = 0.0f;
        #pragma unroll
        for (int k = 0; k < 128; k += 4) {
            float4 hv = *(const float4*)&hl[r][k];
            acc += hv.x * Wl[(k + 0) * 128 + col];
            acc += hv.y * Wl[(k + 1) * 128 + col];
            acc += hv.z * Wl[(k + 2) * 128 + col];
            acc += hv.w * Wl[(k + 3) * 128 + col];
        }
        int row = row0 + r;
        if (row < N) t[(size_t)row * 128 + col] = acc;
        __syncthreads();
    }
}
__global__ __launch_bounds__(256) void init_self_kernel(const float4* __restrict__ t4,
                                                        const float* __restrict__ dinv,
                                                        const float* __restrict__ b,
                                                        float4* __restrict__ out, int N) {
    int idx = blockIdx.x * blockDim.x + threadIdx.x;
    int v = idx >> 5, c = idx & 31;
    if (v >= N) return;
    float di = dinv[v];
    float s = di * di;
    float4 x = t4[(size_t)v * 32 + c];
    float4 bb = ((const float4*)b)[c];
    out[(size_t)v * 32 + c] = make_float4(fmaf(x.x, s, bb.x), fmaf(x.y, s, bb.y),
                                          fmaf(x.z, s, bb.z), fmaf(x.w, s, bb.w));
}
__global__ __launch_bounds__(256) void init_final_kernel(const float4* __restrict__ t4,
                                                         const float* __restrict__ dinv,
                                                         const float* __restrict__ bmu,
                                                         const float* __restrict__ bls,
                                                         float4* __restrict__ out4, int N) {
    int idx = blockIdx.x * blockDim.x + threadIdx.x;
    int v = idx >> 5, c = idx & 31;
    if (v >= N) return;
    int half = c >> 4, cc = c & 15;
    float di = dinv[v];
    float s = di * di;
    float4 x = t4[(size_t)v * 32 + c];
    float4 bb = half ? ((const float4*)bls)[cc] : ((const float4*)bmu)[cc];
    out4[(size_t)half * N * 16 + (size_t)v * 16 + cc] =
        make_float4(fmaf(x.x, s, bb.x), fmaf(x.y, s, bb.y),
                    fmaf(x.z, s, bb.z), fmaf(x.w, s, bb.w));
}
__global__ __launch_bounds__(256) void agg_edge_kernel(const float4* __restrict__ t4,
                                                       const int* __restrict__ src,
                                                       const int* __restrict__ dst,
                                                       const float* __restrict__ dinv,
                                                       float* __restrict__ out, int E) {
    int idx = blockIdx.x * blockDim.x + threadIdx.x;
    int e = idx >> 5, c = idx & 31;
    if (e >= E) return;
    int s = src[e], d = dst[e];
    float w = dinv[s] * dinv[d];
    float4 v = t4[(size_t)s * 32 + c];
    float* o = out + (size_t)d * 128 + c * 4;
    unsafeAtomicAdd(o + 0, v.x * w);
    unsafeAtomicAdd(o + 1, v.y * w);
    unsafeAtomicAdd(o + 2, v.z * w);
    unsafeAtomicAdd(o + 3, v.w * w);
}
__global__ __launch_bounds__(256) void agg_edge_final_kernel(const float4* __restrict__ t4,
                                                             const int* __restrict__ src,
                                                             const int* __restrict__ dst,
                                                             const float* __restrict__ dinv,
                                                             float* __restrict__ out, int N, int E) {
    int idx = blockIdx.x * blockDim.x + threadIdx.x;
    int e = idx >> 5, c = idx & 31;
    if (e >= E) return;
    int s = src[e], d = dst[e];
    int half = c >> 4, cc = c & 15;
    float w = dinv[s] * dinv[d];
    float4 v = t4[(size_t)s * 32 + c];
    float* o = out + (size_t)half * N * 64 + (size_t)d * 64 + cc * 4;
    unsafeAtomicAdd(o + 0, v.x * w);
    unsafeAtomicAdd(o + 1, v.y * w);
    unsafeAtomicAdd(o + 2, v.z * w);
    unsafeAtomicAdd(o + 3, v.w * w);
}

// ---------------- launch ----------------
extern "C" void kernel_launch(void* const* d_in, const int* in_sizes, int n_in,
                              void* d_out, int out_size, void* d_ws, size_t ws_size,
                              hipStream_t stream) {
    const float* x   = (const float*)d_in[0];
    const int*   ei  = (const int*)d_in[1];
    const float* W1  = (const float*)d_in[2];
    const float* b1  = (const float*)d_in[3];
    const float* W2  = (const float*)d_in[4];
    const float* b2  = (const float*)d_in[5];
    const float* Wmu = (const float*)d_in[6];
    const float* bmu = (const float*)d_in[7];
    const float* Wls = (const float*)d_in[8];
    const float* bls = (const float*)d_in[9];

    const int N = in_sizes[0] / 128;
    const int E = in_sizes[1] / 2;
    const int* src = ei;
    const int* dst = ei + E;

    float* out = (float*)d_out;

    auto align256 = [](size_t o) { return (o + 255) & ~(size_t)255; };
    const int B1 = (N + SCAN_CHUNK - 1) / SCAN_CHUNK;

    size_t off = 0;
    size_t o_dinv   = off; off = align256(off + (size_t)N * 4);
    size_t o_t      = off; off = align256(off + (size_t)N * 128 * 4);
    size_t o_rowptr = off; off = align256(off + (size_t)(N + 1) * 4);
    size_t o_cursor = off; off = align256(off + (size_t)N * 4);
    size_t o_bsum   = off; off = align256(off + (size_t)B1 * 4);
    size_t o_col    = off; off = align256(off + (size_t)E * 4);
    size_t o_wt     = off; off = align256(off + (size_t)3 * 128 * 128 * 2);
    size_t need = off;

    float*  dinv = (float*)((char*)d_ws + o_dinv);
    float*  tf   = (float*)((char*)d_ws + o_t);
    __half* th   = (__half*)((char*)d_ws + o_t);
    __half* hh   = (__half*)((char*)d_ws + o_t) + (size_t)N * 128;

    const int TB = 256;
    int gN = (N + TB - 1) / TB;
    int gE = (E + TB - 1) / TB;
    int ntiles = (N + MT_ROWS - 1) / MT_ROWS;

    if (ws_size >= need) {
        int* rowptr = (int*)((char*)d_ws + o_rowptr);
        int* cursor = (int*)((char*)d_ws + o_cursor);
        int* bsum   = (int*)((char*)d_ws + o_bsum);
        int* col    = (int*)((char*)d_ws + o_col);
        __half* wt1 = (__half*)((char*)d_ws + o_wt);
        __half* wt2 = wt1 + 128 * 128;
        __half* wt3 = wt2 + 128 * 128;

        const bool vec4 = ((E & 3) == 0) && ((((uintptr_t)ei) & 15) == 0);
        const int E4 = E >> 2;
        int gE4 = (E4 + TB - 1) / TB;

        int pshift = 0;
        while (((N - 1) >> pshift) >= NPART) ++pshift;

        convwt_all_kernel<<<192, TB, 0, stream>>>(W1, W2, Wmu, Wls, wt1);

        hipMemsetAsync(cursor, 0, (size_t)N * 4, stream);
        if (vec4)
            cnt_count4_kernel<<<gE4, TB, 0, stream>>>((const int4*)dst, cursor, E4);
        else
            cnt_count_kernel<<<gE, TB, 0, stream>>>(dst, cursor, E);
        scan_reduce_kernel<<<B1, TB, 0, stream>>>(cursor, bsum, N);
        scan_bsum_kernel<<<1, 64, 0, stream>>>(bsum, B1, rowptr + N, E);
        scan_write_kernel<<<B1, TB, 0, stream>>>(cursor, bsum, rowptr, cursor, dinv, N);
        if (vec4)
            csr_fill_part4_kernel<<<gE4 * NPART, TB, 0, stream>>>((const int4*)src, (const int4*)dst,
                                                                  cursor, col, E4, pshift);
        else
            csr_fill_kernel<<<gE, TB, 0, stream>>>(src, dst, cursor, col, E);

        int gPull = (N + 15) / 16;
        gemm_mfma<<<1024, TB, 0, stream>>>(x, 1, wt1, dinv, th, N, ntiles);
        agg_pull_h16_kernel<<<gPull, TB, 0, stream>>>(th, rowptr, col, dinv, b1, hh, N);
        gemm_mfma<<<1024, TB, 0, stream>>>(hh, 0, wt2, dinv, th, N, ntiles);
        agg_pull_h16_kernel<<<gPull, TB, 0, stream>>>(th, rowptr, col, dinv, b2, hh, N);
        gemm_mfma<<<1024, TB, 0, stream>>>(hh, 0, wt3, dinv, th, N, ntiles);
        agg_pull_final_h_kernel<<<gPull, TB, 0, stream>>>(th, rowptr, col, dinv, bmu, bls, out, N);
    } else {
        int gN32  = (N * 32 + TB - 1) / TB;
        int gE32h = (int)(((long long)E * 32 + TB - 1) / TB);
        deg_init_kernel<<<gN, TB, 0, stream>>>(dinv, N);
        deg_count_kernel<<<gE, TB, 0, stream>>>(dst, dinv, E);
        deg_rsqrt_kernel<<<gN, TB, 0, stream>>>(dinv, N);

        gemm128_kernel<<<2048, TB, 0, stream>>>(x, W1, nullptr, tf, N, 0);
        init_self_kernel<<<gN32, TB, 0, stream>>>((const float4*)tf, dinv, b1, (float4*)out, N);
        agg_edge_kernel<<<gE32h, TB, 0, stream>>>((const float4*)tf, src, dst, dinv, out, E);

        gemm128_kernel<<<2048, TB, 0, stream>>>(out, W2, nullptr, tf, N, 1);
        init_self_kernel<<<gN32, TB, 0, stream>>>((const float4*)tf, dinv, b2, (float4*)out, N);
        agg_edge_kernel<<<gE32h, TB, 0, stream>>>((const float4*)tf, src, dst, dinv, out, E);

        gemm128_kernel<<<2048, TB, 0, stream>>>(out, Wmu, Wls, tf, N, 1);
        init_final_kernel<<<gN32, TB, 0, stream>>>((const float4*)tf, dinv, bmu, bls, (float4*)out, N);
        agg_edge_final_kernel<<<gE32h, TB, 0, stream>>>((const float4*)tf, src, dst, dinv, out, N, E);
    }
}